// Round 1
// baseline (151.078 us; speedup 1.0000x reference)
//
#include <hip/hip_runtime.h>

// NegativeSamplingLinear: out[b, 0]   = dot(x[b], W[y[b]])
//                         out[b, 1+k] = dot(x[b], W[neg_idx[b,k]])
// B=1024, D=512, K=512, V=100000. All fp32; indices arrive as int32 per harness.

constexpr int D_DIM = 512;
constexpr int K_NEG = 512;
constexpr int ROWS  = K_NEG + 1;  // 513

__global__ __launch_bounds__(256) void nsl_gather_dot_kernel(
    const float* __restrict__ x,       // [B, D]
    const int*   __restrict__ y,       // [B]
    const int*   __restrict__ neg,     // [B, K]
    const float* __restrict__ W,       // [V, D]
    float*       __restrict__ out)     // [B, ROWS]
{
    const int b    = blockIdx.x;
    const int t    = threadIdx.x;
    const int lane = t & 63;
    const int wid  = t >> 6;           // 4 waves per block

    // Stage the 513 row indices for this sample into LDS.
    __shared__ int idxs[ROWS];
    for (int r = t; r < ROWS; r += 256)
        idxs[r] = (r == 0) ? y[b] : neg[b * K_NEG + (r - 1)];

    // x[b] fragment in registers: lane covers d in [lane*4, lane*4+4) and
    // [1024 + lane*4 ...) -- same lane->d map used for W rows, so the dot
    // product is consistent without any cross-lane data movement for x.
    const float4* xp = reinterpret_cast<const float4*>(x + (size_t)b * D_DIM);
    const float4 xa = xp[lane];
    const float4 xb = xp[lane + 64];

    __syncthreads();

    float* outb = out + (size_t)b * ROWS;

    // Each wave processes rows in pairs {r0, r0+1}, stride 8 across 4 waves.
    for (int r0 = wid * 2; r0 < ROWS; r0 += 8) {
        const int  r1   = r0 + 1;
        const bool has1 = (r1 < ROWS);
        const int  row0 = idxs[r0];
        const int  row1 = idxs[has1 ? r1 : r0];

        const float4* w0 = reinterpret_cast<const float4*>(W + (size_t)row0 * D_DIM);
        const float4* w1 = reinterpret_cast<const float4*>(W + (size_t)row1 * D_DIM);

        // Two independent coalesced row reads (4 x 16B/lane in flight).
        const float4 a0 = w0[lane];
        const float4 b0 = w0[lane + 64];
        const float4 a1 = w1[lane];
        const float4 b1 = w1[lane + 64];

        float acc0;
        acc0 = a0.x * xa.x;
        acc0 = fmaf(a0.y, xa.y, acc0);
        acc0 = fmaf(a0.z, xa.z, acc0);
        acc0 = fmaf(a0.w, xa.w, acc0);
        acc0 = fmaf(b0.x, xb.x, acc0);
        acc0 = fmaf(b0.y, xb.y, acc0);
        acc0 = fmaf(b0.z, xb.z, acc0);
        acc0 = fmaf(b0.w, xb.w, acc0);

        float acc1;
        acc1 = a1.x * xa.x;
        acc1 = fmaf(a1.y, xa.y, acc1);
        acc1 = fmaf(a1.z, xa.z, acc1);
        acc1 = fmaf(a1.w, xa.w, acc1);
        acc1 = fmaf(b1.x, xb.x, acc1);
        acc1 = fmaf(b1.y, xb.y, acc1);
        acc1 = fmaf(b1.z, xb.z, acc1);
        acc1 = fmaf(b1.w, xb.w, acc1);

        // Wave-wide butterfly reduction over all 64 lanes, both rows.
        #pragma unroll
        for (int off = 32; off > 0; off >>= 1) {
            acc0 += __shfl_xor(acc0, off, 64);
            acc1 += __shfl_xor(acc1, off, 64);
        }

        if (lane == 0) {
            outb[r0] = acc0;
            if (has1) outb[r1] = acc1;
        }
    }
}

extern "C" void kernel_launch(void* const* d_in, const int* in_sizes, int n_in,
                              void* d_out, int out_size, void* d_ws, size_t ws_size,
                              hipStream_t stream) {
    const float* x   = (const float*)d_in[0];
    const int*   y   = (const int*)d_in[1];
    const int*   neg = (const int*)d_in[2];
    const float* W   = (const float*)d_in[3];
    float*       out = (float*)d_out;

    const int B = in_sizes[1];  // y has one entry per sample (1024)

    nsl_gather_dot_kernel<<<B, 256, 0, stream>>>(x, y, neg, W, out);
}